// Round 10
// baseline (837.651 us; speedup 1.0000x reference)
//
#include <hip/hip_runtime.h>
#include <hip/hip_bf16.h>
#include <cstdint>
#include <cstddef>

// Problem constants
#define TOKENS 4096       // B*T = 2*2048
#define CDIM   1024
#define HDIM   2730
#define HPAD2  2816       // HDIM padded to multiple of 128
#define NEXP   8
#define NPAIR  (TOKENS * 2)
#define NTB1   (HPAD2 / 128)   // 22 n-tiles for gemm1 (N-tile 128, dual)
#define NTB2   (CDIM / 128)    // 8 n-tiles for gemm2
#define NT1    (CDIM / 64)     // 16 K-steps gemm1
#define NT2    (HPAD2 / 64)    // 44 K-steps gemm2

typedef __bf16 bf16_t;
typedef bf16_t bf16x8 __attribute__((ext_vector_type(8)));
typedef float  f32x4  __attribute__((ext_vector_type(4)));

// fp32 -> bf16, round-to-nearest-even
static __device__ __forceinline__ unsigned short f2bf(float f) {
    union { float f; unsigned int u; } v; v.f = f;
    unsigned int u = v.u;
    return (unsigned short)((u + 0x7FFFu + ((u >> 16) & 1u)) >> 16);
}
static __device__ __forceinline__ unsigned int pack2(float a, float b) {
    return (unsigned int)f2bf(a) | ((unsigned int)f2bf(b) << 16);
}

// async global->LDS, 16B per lane; LDS dest is wave-uniform base + lane*16
typedef __attribute__((address_space(3))) unsigned int lds_uint;
typedef const __attribute__((address_space(1))) unsigned int glob_uint;
static __device__ __forceinline__ void gl_lds16(const void* g, void* l) {
    __builtin_amdgcn_global_load_lds((glob_uint*)g, (lds_uint*)l, 16, 0, 0);
}

// meta layout (ints):
// [0..7] expert counts, [8..16] offsets, [17] nblk1, [18] unified tile ctr,
// [20] nblk2, [21] ntile1, [22] ntile_total, [24..31] scatter cursors,
// [32..111]  table1 (e,m0) pairs, m-step 256  (<=40 blocks)
// [128..271] table2 (e,m0) pairs, m-step 128  (<=72 blocks)
// [320..391] parent gemm1 block id for each gemm2 block
// [400..439] done counters per gemm1 m-block

__global__ void moe_init(int* meta) {
    meta[threadIdx.x] = 0;      // 512 threads zero meta[0..511]
}

// Router: one wave per token.
__global__ __launch_bounds__(256) void moe_router(
    const float* __restrict__ x, const float* __restrict__ gw,
    int* __restrict__ meta, int* __restrict__ tok_idx, float* __restrict__ tok_w)
{
    int wave = threadIdx.x >> 6;
    int lane = threadIdx.x & 63;
    int t = blockIdx.x * 4 + wave;

    float acc[NEXP];
#pragma unroll
    for (int e = 0; e < NEXP; ++e) acc[e] = 0.f;

    const float4* xr = (const float4*)(x + (size_t)t * CDIM);
#pragma unroll
    for (int it = 0; it < 4; ++it) {
        int c4 = it * 64 + lane;
        float4 xv = xr[c4];
#pragma unroll
        for (int e = 0; e < NEXP; ++e) {
            float4 gv = ((const float4*)(gw + e * CDIM))[c4];
            acc[e] += xv.x * gv.x + xv.y * gv.y + xv.z * gv.z + xv.w * gv.w;
        }
    }
#pragma unroll
    for (int e = 0; e < NEXP; ++e) {
#pragma unroll
        for (int off = 32; off > 0; off >>= 1)
            acc[e] += __shfl_xor(acc[e], off, 64);
    }
    if (lane == 0) {
        int e0 = 0; float v0 = acc[0];
#pragma unroll
        for (int e = 1; e < NEXP; ++e) if (acc[e] > v0) { v0 = acc[e]; e0 = e; }
        int e1 = -1; float v1 = -3.0e38f;
#pragma unroll
        for (int e = 0; e < NEXP; ++e) if (e != e0 && acc[e] > v1) { v1 = acc[e]; e1 = e; }
        float w0 = 1.f / (1.f + __expf(v1 - v0));   // softmax over {v0,v1}
        tok_idx[2 * t] = e0; tok_idx[2 * t + 1] = e1;
        tok_w[2 * t] = w0;  tok_w[2 * t + 1] = 1.f - w0;
        atomicAdd(&meta[e0], 1);
        atomicAdd(&meta[e1], 1);
    }
}

// prefix-sum + both m-block tables + gemm2->gemm1 parent mapping
__global__ void moe_scan(int* meta) {
    if (threadIdx.x == 0) {
        int s = 0;
        for (int e = 0; e < NEXP; ++e) { meta[8 + e] = s; s += meta[e]; }
        meta[16] = s;
        int nb1 = 0, nb2 = 0;
        for (int e = 0; e < NEXP; ++e) {
            int beg = meta[8 + e], end = meta[8 + e] + meta[e];
            int g1base = nb1;
            for (int m0 = beg; m0 < end; m0 += 256) {
                meta[32 + 2 * nb1] = e;
                meta[33 + 2 * nb1] = m0;
                ++nb1;
            }
            int k2 = 0;
            for (int m0 = beg; m0 < end; m0 += 128) {
                meta[128 + 2 * nb2] = e;
                meta[129 + 2 * nb2] = m0;
                meta[320 + nb2] = g1base + (k2 >> 1);   // parent gemm1 block
                ++k2; ++nb2;
            }
        }
        meta[17] = nb1;
        meta[20] = nb2;
        meta[21] = nb1 * NTB1;
        meta[22] = nb1 * NTB1 + nb2 * NTB2;
    }
}

__global__ __launch_bounds__(256) void moe_scatter(
    const int* __restrict__ tok_idx, const float* __restrict__ tok_w, int* meta,
    int* __restrict__ pair_token, float* __restrict__ pair_w)
{
    int t = blockIdx.x * 256 + threadIdx.x;
    if (t >= TOKENS) return;
#pragma unroll
    for (int k = 0; k < 2; ++k) {
        int e = tok_idx[2 * t + k];
        int pos = atomicAdd(&meta[24 + e], 1);
        int slot = meta[8 + e] + pos;
        pair_token[slot] = t;
        pair_w[slot] = tok_w[2 * t + k];
    }
}

// Gather x rows per pair, fp32 -> bf16. 8 rows per block.
__global__ __launch_bounds__(256) void moe_gather(
    const float* __restrict__ x, const int* __restrict__ pair_token,
    unsigned short* __restrict__ Xg)
{
    int base = blockIdx.x * 8;
    int i = threadIdx.x;
#pragma unroll
    for (int r = 0; r < 8; ++r) {
        int row = base + r;
        int t = pair_token[row];
        float4 v = ((const float4*)(x + (size_t)t * CDIM))[i];
        ushort4 o;
        o.x = f2bf(v.x); o.y = f2bf(v.y); o.z = f2bf(v.z); o.w = f2bf(v.w);
        ((ushort4*)(Xg + (size_t)row * CDIM))[i] = o;
    }
}

// ---------------- weight conversion (once) ----------------
__global__ __launch_bounds__(256) void conv_w12(
    const float* __restrict__ w1, const float* __restrict__ w2,
    unsigned short* __restrict__ w1b, unsigned short* __restrict__ w2b)
{
    int e = blockIdx.y;
    const float* wsrc = blockIdx.z ? w2 : w1;
    unsigned short* wdst = blockIdx.z ? w2b : w1b;
    int col = threadIdx.x * 4;
#pragma unroll
    for (int r = 0; r < 8; ++r) {
        int row = blockIdx.x * 8 + r;
        unsigned short* dst = wdst + ((size_t)e * HPAD2 + row) * CDIM;
        uint2 pv;
        if (row < HDIM) {
            float4 a = *(const float4*)(wsrc + ((size_t)e * HDIM + row) * CDIM + col);
            pv.x = pack2(a.x, a.y); pv.y = pack2(a.z, a.w);
        } else {
            pv = uint2{0, 0};
        }
        *(uint2*)(dst + col) = pv;
    }
}

__global__ __launch_bounds__(256) void conv_w3(
    const float* __restrict__ w3, unsigned short* __restrict__ w3b)
{
    int e = blockIdx.y;
#pragma unroll
    for (int r = 0; r < 8; ++r) {
        int row = blockIdx.x * 8 + r;
        const float* src = w3 + ((size_t)e * CDIM + row) * HDIM;
        unsigned short* dst = w3b + ((size_t)e * CDIM + row) * HPAD2;
        for (int ch = threadIdx.x; ch < HPAD2 / 8; ch += 256) {
            int h = ch * 8;
            uint4 pv;
            if (h + 8 <= HDIM) {
                float2 a = *(const float2*)(src + h);
                float2 b = *(const float2*)(src + h + 2);
                float2 c = *(const float2*)(src + h + 4);
                float2 d = *(const float2*)(src + h + 6);
                pv.x = pack2(a.x, a.y); pv.y = pack2(b.x, b.y);
                pv.z = pack2(c.x, c.y); pv.w = pack2(d.x, d.y);
            } else if (h < HDIM) {
                float v[8];
#pragma unroll
                for (int q = 0; q < 8; ++q) v[q] = (h + q < HDIM) ? src[h + q] : 0.f;
                pv.x = pack2(v[0], v[1]); pv.y = pack2(v[2], v[3]);
                pv.z = pack2(v[4], v[5]); pv.w = pack2(v[6], v[7]);
            } else {
                pv = uint4{0, 0, 0, 0};
            }
            *(uint4*)(dst + h) = pv;
        }
    }
}

// ---------------- fused grouped GEMMs: one persistent kernel ----------------
// Unified dynamic tile counter; tiles [0, ntile1) = gemm1, [ntile1, ntileT) = gemm2.
// gemm2 tiles spin on per-gemm1-m-block done counters (producer/consumer across blocks;
// release = __threadfence + device atomicAdd, acquire = atomic poll + __threadfence).
// grid 256 x 512 thr, 128KB LDS -> all blocks co-resident -> spin is deadlock-free.
#define SWZ(row, ch) (((row) << 6) + ((((ch) ^ ((row) & 7))) << 3))

__global__ __launch_bounds__(512, 2) void moe_gemms(
    const unsigned short* __restrict__ Xg,
    const unsigned short* __restrict__ w1b, const unsigned short* __restrict__ w2b,
    const unsigned short* __restrict__ w3b,
    const float* __restrict__ pair_w, int* __restrict__ meta,
    const int* __restrict__ pair_token,
    unsigned short* __restrict__ act, float* __restrict__ out)
{
    __shared__ unsigned short sA[2][256 * 64];   // 32 KB x2
    __shared__ unsigned short sB[2][256 * 64];   // 32 KB x2
    __shared__ int sTile;

    int tid = threadIdx.x;
    int lane = tid & 63;
    int wv = tid >> 6;               // 0..7
    int l3 = lane >> 3;
    int l15 = lane & 15, l4 = lane >> 4;
    int srcc = (((lane & 7) ^ l3) << 3);   // pre-swizzled source column (elements)

    int ntile1 = meta[21];
    int ntileT = meta[22];

    for (;;) {
        if (tid == 0) sTile = atomicAdd(&meta[18], 1);
        __syncthreads();
        int t = sTile;
        if (t >= ntileT) break;

        if (t < ntile1) {
            // ================= GEMM1 tile (R5 2-phase form) =================
            // tile 256m x 128n-dual, 8 waves (2m x 4n), wave 128m x 32n(dual)
            int bm = t / NTB1, bn = t - bm * NTB1;   // bm-major: m-block completes early
            int e  = meta[32 + 2 * bm];
            int m0 = meta[33 + 2 * bm];
            int mEnd = meta[9 + e];
            int mEndm1 = mEnd - 1;
            int n0 = bn * 128;
            int wm = wv >> 2, wn = wv & 3;

            const unsigned short* w1e = w1b + (size_t)e * HPAD2 * CDIM + (size_t)n0 * CDIM;
            const unsigned short* w2e = w2b + (size_t)e * HPAD2 * CDIM + (size_t)n0 * CDIM;
            const unsigned short* bbase = (wv < 4) ? w1e : w2e;

            f32x4 acc1[8][2], acc2[8][2];
#pragma unroll
            for (int i = 0; i < 8; ++i)
#pragma unroll
                for (int j = 0; j < 2; ++j) {
                    acc1[i][j] = {0.f, 0.f, 0.f, 0.f};
                    acc2[i][j] = {0.f, 0.f, 0.f, 0.f};
                }

            auto STAGE = [&](int b, int kk) {
                int k0 = kk * 64;
#pragma unroll
                for (int i_ = 0; i_ < 4; ++i_) {
                    int seg = wv * 4 + i_;
                    int arow = seg * 8 + l3;
                    int grow = m0 + arow; if (grow > mEndm1) grow = mEndm1;
                    gl_lds16(Xg + (size_t)grow * CDIM + k0 + srcc, sA[b] + seg * 512);
                    int bseg = (wv < 4) ? seg : seg - 16;
                    gl_lds16(bbase + (size_t)(bseg * 8 + l3) * CDIM + k0 + srcc, sB[b] + seg * 512);
                }
            };

            STAGE(0, 0);
            __syncthreads();
            for (int t_ = 0; t_ < NT1; ++t_) {
                int cur = t_ & 1;
                if (t_ + 1 < NT1) STAGE(cur ^ 1, t_ + 1);
#pragma unroll
                for (int ks = 0; ks < 2; ++ks) {
                    int kch = ks * 4 + l4;
                    bf16x8 af[8], b1f[2], b2f[2];
#pragma unroll
                    for (int i = 0; i < 8; ++i)
                        af[i] = *(const bf16x8*)(sA[cur] + SWZ(wm * 128 + i * 16 + l15, kch));
#pragma unroll
                    for (int j = 0; j < 2; ++j) {
                        int r1 = wn * 32 + j * 16 + l15;
                        b1f[j] = *(const bf16x8*)(sB[cur] + SWZ(r1, kch));
                        b2f[j] = *(const bf16x8*)(sB[cur] + SWZ(128 + r1, kch));
                    }
#pragma unroll
                    for (int i = 0; i < 8; ++i)
#pragma unroll
                        for (int j = 0; j < 2; ++j) {
                            acc1[i][j] = __builtin_amdgcn_mfma_f32_16x16x32_bf16(af[i], b1f[j], acc1[i][j], 0, 0, 0);
                            acc2[i][j] = __builtin_amdgcn_mfma_f32_16x16x32_bf16(af[i], b2f[j], acc2[i][j], 0, 0, 0);
                        }
                }
                __syncthreads();
            }

            // epilogue: act = silu(h1)*h2*pair_w (bf16)
#pragma unroll
            for (int i = 0; i < 8; ++i) {
                int rbase = m0 + wm * 128 + i * 16 + (l4 << 2);
#pragma unroll
                for (int r = 0; r < 4; ++r) {
                    int grow = rbase + r;
                    if (grow >= mEnd) continue;
                    float pw = pair_w[grow];
                    size_t rowoff = (size_t)grow * HPAD2;
#pragma unroll
                    for (int j = 0; j < 2; ++j) {
                        int gcol = n0 + wn * 32 + j * 16 + l15;
                        float h1 = acc1[i][j][r], h2 = acc2[i][j][r];
                        float a = (h1 / (1.f + __expf(-h1))) * h2 * pw;
                        act[rowoff + gcol] = f2bf(a);
                    }
                }
            }
            // release: flush act stores device-wide, then signal tile completion
            __threadfence();
            __syncthreads();
            if (tid == 0) atomicAdd(&meta[400 + bm], 1);
        } else {
            // ================= GEMM2 tile (R5 form) =================
            // tile 128m x 128n, 8 waves (2m x 4n), wave 64m x 32n
            int t2 = t - ntile1;
            int bm = t2 >> 3, bn = t2 & 7;
            int parent = meta[320 + bm];
            if (tid == 0) {
                while (__hip_atomic_load(&meta[400 + parent], __ATOMIC_RELAXED,
                                         __HIP_MEMORY_SCOPE_AGENT) < NTB1)
                    __builtin_amdgcn_s_sleep(32);
            }
            __syncthreads();
            __threadfence();   // acquire: invalidate stale L2 before reading act

            int e  = meta[128 + 2 * bm];
            int m0 = meta[129 + 2 * bm];
            int mEnd = meta[9 + e];
            int mEndm1 = mEnd - 1;
            int n0 = bn * 128;
            int wm = wv >> 2, wn = wv & 3;

            const unsigned short* w3e = w3b + (size_t)e * CDIM * HPAD2 + (size_t)n0 * HPAD2;

            f32x4 acc[4][2];
#pragma unroll
            for (int i = 0; i < 4; ++i)
#pragma unroll
                for (int j = 0; j < 2; ++j) acc[i][j] = {0.f, 0.f, 0.f, 0.f};

            auto STAGE2 = [&](int b, int kk) {
                int k0 = kk * 64;
#pragma unroll
                for (int i_ = 0; i_ < 2; ++i_) {
                    int seg = wv * 2 + i_;
                    int row = seg * 8 + l3;
                    int grow = m0 + row; if (grow > mEndm1) grow = mEndm1;
                    gl_lds16(act + (size_t)grow * HPAD2 + k0 + srcc, sA[b] + seg * 512);
                    gl_lds16(w3e + (size_t)row * HPAD2 + k0 + srcc, sB[b] + seg * 512);
                }
            };

            STAGE2(0, 0);
            __syncthreads();
            for (int t_ = 0; t_ < NT2; ++t_) {
                int cur = t_ & 1;
                if (t_ + 1 < NT2) STAGE2(cur ^ 1, t_ + 1);
#pragma unroll
                for (int ks = 0; ks < 2; ++ks) {
                    int kch = ks * 4 + l4;
                    bf16x8 af[4], bf[2];
#pragma unroll
                    for (int i = 0; i < 4; ++i)
                        af[i] = *(const bf16x8*)(sA[cur] + SWZ(wm * 64 + i * 16 + l15, kch));
#pragma unroll
                    for (int j = 0; j < 2; ++j)
                        bf[j] = *(const bf16x8*)(sB[cur] + SWZ(wn * 32 + j * 16 + l15, kch));
#pragma unroll
                    for (int i = 0; i < 4; ++i)
#pragma unroll
                        for (int j = 0; j < 2; ++j)
                            acc[i][j] = __builtin_amdgcn_mfma_f32_16x16x32_bf16(af[i], bf[j], acc[i][j], 0, 0, 0);
                }
                __syncthreads();
            }

#pragma unroll
            for (int i = 0; i < 4; ++i) {
                int rbase = m0 + wm * 64 + i * 16 + (l4 << 2);
#pragma unroll
                for (int r = 0; r < 4; ++r) {
                    int grow = rbase + r;
                    if (grow >= mEnd) continue;
                    int tok = pair_token[grow];
                    float* orow = out + (size_t)tok * CDIM;
#pragma unroll
                    for (int j = 0; j < 2; ++j) {
                        int gcol = n0 + wn * 32 + j * 16 + l15;
                        atomicAdd(orow + gcol, acc[i][j][r]);
                    }
                }
            }
        }
        __syncthreads();   // protect sTile + LDS before next grab
    }
}

extern "C" void kernel_launch(void* const* d_in, const int* in_sizes, int n_in,
                              void* d_out, int out_size, void* d_ws, size_t ws_size,
                              hipStream_t stream)
{
    const float* x  = (const float*)d_in[0];
    const float* gw = (const float*)d_in[1];
    const float* w1 = (const float*)d_in[2];
    const float* w2 = (const float*)d_in[3];
    const float* w3 = (const float*)d_in[4];
    float* out = (float*)d_out;

    char* ws = (char*)d_ws;
    size_t off = 0;
    auto alloc = [&](size_t bytes) -> void* {
        off = (off + 255) & ~(size_t)255;
        void* p = ws + off;
        off += bytes;
        return p;
    };
    int*   meta       = (int*)alloc(512 * sizeof(int));
    int*   tok_idx    = (int*)alloc((size_t)NPAIR * sizeof(int));
    float* tok_w      = (float*)alloc((size_t)NPAIR * sizeof(float));
    int*   pair_token = (int*)alloc((size_t)NPAIR * sizeof(int));
    float* pair_w     = (float*)alloc((size_t)NPAIR * sizeof(float));
    unsigned short* Xg  = (unsigned short*)alloc((size_t)NPAIR * CDIM * 2);
    unsigned short* act = (unsigned short*)alloc((size_t)NPAIR * HPAD2 * 2);
    unsigned short* w1b = (unsigned short*)alloc((size_t)NEXP * HPAD2 * CDIM * 2);
    unsigned short* w2b = (unsigned short*)alloc((size_t)NEXP * HPAD2 * CDIM * 2);
    unsigned short* w3b = (unsigned short*)alloc((size_t)NEXP * CDIM * HPAD2 * 2);
    (void)ws_size; (void)in_sizes; (void)n_in;

    hipMemsetAsync(d_out, 0, (size_t)out_size * sizeof(float), stream);

    moe_init<<<1, 512, 0, stream>>>(meta);
    moe_router<<<TOKENS / 4, 256, 0, stream>>>(x, gw, meta, tok_idx, tok_w);
    moe_scan<<<1, 64, 0, stream>>>(meta);
    moe_scatter<<<TOKENS / 256, 256, 0, stream>>>(tok_idx, tok_w, meta, pair_token, pair_w);
    moe_gather<<<NPAIR / 8, 256, 0, stream>>>(x, pair_token, Xg);
    conv_w12<<<dim3(HPAD2 / 8, NEXP, 2), 256, 0, stream>>>(w1, w2, w1b, w2b);
    conv_w3<<<dim3(CDIM / 8, NEXP), 256, 0, stream>>>(w3, w3b);
    moe_gemms<<<256, 512, 0, stream>>>(Xg, w1b, w2b, w3b, pair_w, meta, pair_token, act, out);
}

// Round 11
// 507.257 us; speedup vs baseline: 1.6513x; 1.6513x over previous
//
#include <hip/hip_runtime.h>
#include <hip/hip_bf16.h>
#include <cstdint>
#include <cstddef>

// Problem constants
#define TOKENS 4096       // B*T = 2*2048
#define CDIM   1024
#define HDIM   2730
#define HPAD2  2816       // HDIM padded to multiple of 128
#define NEXP   8
#define NPAIR  (TOKENS * 2)
#define NTB1   (HPAD2 / 128)   // 22 n-tiles for gemm1 (N-tile 128, dual)
#define NTB2   (CDIM / 128)    // 8 n-tiles for gemm2
#define NT1    (CDIM / 64)     // 16 K-steps gemm1
#define NT2    (HPAD2 / 64)    // 44 K-steps gemm2

typedef __bf16 bf16_t;
typedef bf16_t bf16x8 __attribute__((ext_vector_type(8)));
typedef float  f32x4  __attribute__((ext_vector_type(4)));

// fp32 -> bf16, round-to-nearest-even
static __device__ __forceinline__ unsigned short f2bf(float f) {
    union { float f; unsigned int u; } v; v.f = f;
    unsigned int u = v.u;
    return (unsigned short)((u + 0x7FFFu + ((u >> 16) & 1u)) >> 16);
}
static __device__ __forceinline__ unsigned int pack2(float a, float b) {
    return (unsigned int)f2bf(a) | ((unsigned int)f2bf(b) << 16);
}

// async global->LDS, 16B per lane; LDS dest is wave-uniform base + lane*16
typedef __attribute__((address_space(3))) unsigned int lds_uint;
typedef const __attribute__((address_space(1))) unsigned int glob_uint;
static __device__ __forceinline__ void gl_lds16(const void* g, void* l) {
    __builtin_amdgcn_global_load_lds((glob_uint*)g, (lds_uint*)l, 16, 0, 0);
}

// meta layout (ints): [0..7] counts, [8..16] offsets, [17] nblk1, [18] g1 tile ctr,
// [19] g2 tile ctr, [20] nblk2, [24..31] scatter cursors,
// [32..111] table1 (e,m0) step 256, [128..271] table2 (e,m0) step 128

// Zero out[] (1024 blocks x 4096 floats) and meta (block 0). Replaces memset + moe_init.
__global__ __launch_bounds__(256) void moe_zero(int* meta, float* out) {
    int b = blockIdx.x;
    float4 z4 = {0.f, 0.f, 0.f, 0.f};
#pragma unroll
    for (int i = 0; i < 4; ++i)
        ((float4*)out)[(size_t)b * 1024 + i * 256 + threadIdx.x] = z4;
    if (b == 0) {
        meta[threadIdx.x] = 0;
        meta[256 + threadIdx.x] = 0;
    }
}

// Router: one wave per token.
__global__ __launch_bounds__(256) void moe_router(
    const float* __restrict__ x, const float* __restrict__ gw,
    int* __restrict__ meta, int* __restrict__ tok_idx, float* __restrict__ tok_w)
{
    int wave = threadIdx.x >> 6;
    int lane = threadIdx.x & 63;
    int t = blockIdx.x * 4 + wave;

    float acc[NEXP];
#pragma unroll
    for (int e = 0; e < NEXP; ++e) acc[e] = 0.f;

    const float4* xr = (const float4*)(x + (size_t)t * CDIM);
#pragma unroll
    for (int it = 0; it < 4; ++it) {
        int c4 = it * 64 + lane;
        float4 xv = xr[c4];
#pragma unroll
        for (int e = 0; e < NEXP; ++e) {
            float4 gv = ((const float4*)(gw + e * CDIM))[c4];
            acc[e] += xv.x * gv.x + xv.y * gv.y + xv.z * gv.z + xv.w * gv.w;
        }
    }
#pragma unroll
    for (int e = 0; e < NEXP; ++e) {
#pragma unroll
        for (int off = 32; off > 0; off >>= 1)
            acc[e] += __shfl_xor(acc[e], off, 64);
    }
    if (lane == 0) {
        int e0 = 0; float v0 = acc[0];
#pragma unroll
        for (int e = 1; e < NEXP; ++e) if (acc[e] > v0) { v0 = acc[e]; e0 = e; }
        int e1 = -1; float v1 = -3.0e38f;
#pragma unroll
        for (int e = 0; e < NEXP; ++e) if (e != e0 && acc[e] > v1) { v1 = acc[e]; e1 = e; }
        float w0 = 1.f / (1.f + __expf(v1 - v0));   // softmax over {v0,v1}
        tok_idx[2 * t] = e0; tok_idx[2 * t + 1] = e1;
        tok_w[2 * t] = w0;  tok_w[2 * t + 1] = 1.f - w0;
        atomicAdd(&meta[e0], 1);
        atomicAdd(&meta[e1], 1);
    }
}

// prefix-sum + two m-block tables (step 256 for gemm1, step 128 for gemm2)
__global__ void moe_scan(int* meta) {
    if (threadIdx.x == 0) {
        int s = 0;
        for (int e = 0; e < NEXP; ++e) { meta[8 + e] = s; s += meta[e]; }
        meta[16] = s;
        int nb1 = 0;
        for (int e = 0; e < NEXP; ++e) {
            int beg = meta[8 + e], end = meta[8 + e] + meta[e];
            for (int m0 = beg; m0 < end; m0 += 256) {
                meta[32 + 2 * nb1] = e;
                meta[33 + 2 * nb1] = m0;
                ++nb1;
            }
        }
        meta[17] = nb1;
        int nb2 = 0;
        for (int e = 0; e < NEXP; ++e) {
            int beg = meta[8 + e], end = meta[8 + e] + meta[e];
            for (int m0 = beg; m0 < end; m0 += 128) {
                meta[128 + 2 * nb2] = e;
                meta[129 + 2 * nb2] = m0;
                ++nb2;
            }
        }
        meta[20] = nb2;
    }
}

__global__ __launch_bounds__(256) void moe_scatter(
    const int* __restrict__ tok_idx, const float* __restrict__ tok_w, int* meta,
    int* __restrict__ pair_token, float* __restrict__ pair_w)
{
    int t = blockIdx.x * 256 + threadIdx.x;
    if (t >= TOKENS) return;
#pragma unroll
    for (int k = 0; k < 2; ++k) {
        int e = tok_idx[2 * t + k];
        int pos = atomicAdd(&meta[24 + e], 1);
        int slot = meta[8 + e] + pos;
        pair_token[slot] = t;
        pair_w[slot] = tok_w[2 * t + k];
    }
}

// Gather x rows per pair, fp32 -> bf16. 8 rows per block.
__global__ __launch_bounds__(256) void moe_gather(
    const float* __restrict__ x, const int* __restrict__ pair_token,
    unsigned short* __restrict__ Xg)
{
    int base = blockIdx.x * 8;
    int i = threadIdx.x;
#pragma unroll
    for (int r = 0; r < 8; ++r) {
        int row = base + r;
        int t = pair_token[row];
        float4 v = ((const float4*)(x + (size_t)t * CDIM))[i];
        ushort4 o;
        o.x = f2bf(v.x); o.y = f2bf(v.y); o.z = f2bf(v.z); o.w = f2bf(v.w);
        ((ushort4*)(Xg + (size_t)row * CDIM))[i] = o;
    }
}

// ---------------- weight conversion (one launch) ----------------
// z=0: w1 -> w1b, z=1: w2 -> w2b (rows >= HDIM zeroed; 16B stores, 2 rows x 128 lanes)
// z=2: w3 -> w3b ([E][CDIM][HPAD2], cols >= HDIM zeroed)
__global__ __launch_bounds__(256) void conv_all(
    const float* __restrict__ w1, const float* __restrict__ w2, const float* __restrict__ w3,
    unsigned short* __restrict__ w1b, unsigned short* __restrict__ w2b,
    unsigned short* __restrict__ w3b)
{
    int e = blockIdx.y;
    int z = blockIdx.z;
    if (z < 2) {
        const float* wsrc = z ? w2 : w1;
        unsigned short* wdst = z ? w2b : w1b;
        int half = threadIdx.x >> 7;            // 0..1
        int col = (threadIdx.x & 127) * 8;      // 8 bf16 = 16B store
#pragma unroll
        for (int r = 0; r < 4; ++r) {
            int row = blockIdx.x * 8 + r * 2 + half;
            unsigned short* dst = wdst + ((size_t)e * HPAD2 + row) * CDIM;
            uint4 pv;
            if (row < HDIM) {
                const float* src = wsrc + ((size_t)e * HDIM + row) * CDIM + col;
                float4 a = *(const float4*)(src);
                float4 b = *(const float4*)(src + 4);
                pv.x = pack2(a.x, a.y); pv.y = pack2(a.z, a.w);
                pv.z = pack2(b.x, b.y); pv.w = pack2(b.z, b.w);
            } else {
                pv = uint4{0, 0, 0, 0};
            }
            *(uint4*)(dst + col) = pv;
        }
    } else {
        if (blockIdx.x >= CDIM / 8) return;
#pragma unroll
        for (int r = 0; r < 8; ++r) {
            int row = blockIdx.x * 8 + r;
            const float* src = w3 + ((size_t)e * CDIM + row) * HDIM;
            unsigned short* dst = w3b + ((size_t)e * CDIM + row) * HPAD2;
            for (int ch = threadIdx.x; ch < HPAD2 / 8; ch += 256) {
                int h = ch * 8;
                uint4 pv;
                if (h + 8 <= HDIM) {
                    float2 a = *(const float2*)(src + h);
                    float2 b = *(const float2*)(src + h + 2);
                    float2 c = *(const float2*)(src + h + 4);
                    float2 d = *(const float2*)(src + h + 6);
                    pv.x = pack2(a.x, a.y); pv.y = pack2(b.x, b.y);
                    pv.z = pack2(c.x, c.y); pv.w = pack2(d.x, d.y);
                } else if (h < HDIM) {
                    float v[8];
#pragma unroll
                    for (int q = 0; q < 8; ++q) v[q] = (h + q < HDIM) ? src[h + q] : 0.f;
                    pv.x = pack2(v[0], v[1]); pv.y = pack2(v[2], v[3]);
                    pv.z = pack2(v[4], v[5]); pv.w = pack2(v[6], v[7]);
                } else {
                    pv = uint4{0, 0, 0, 0};
                }
                *(uint4*)(dst + h) = pv;
            }
        }
    }
}

// ---------------- grouped GEMMs (verbatim R8) ----------------
// LDS row-major [*][64] bf16 with 16B-chunk XOR swizzle (both-sides, rule 21).
#define SWZ(row, ch) (((row) << 6) + ((((ch) ^ ((row) & 7))) << 3))

// GEMM1 (8-phase): tile 256m x 128n-dual (B = w1 rows ‖ w2 rows, 256 LDS rows).
// 512 threads, 8 waves (2m x 4n), wave tile 128m x 32n(dual).
__global__ __launch_bounds__(512, 2) void moe_gemm1(
    const unsigned short* __restrict__ Xg,
    const unsigned short* __restrict__ w1b, const unsigned short* __restrict__ w2b,
    const float* __restrict__ pair_w, int* __restrict__ meta,
    unsigned short* __restrict__ act)
{
    __shared__ unsigned short sA[2][256 * 64];   // 32 KB x2
    __shared__ unsigned short sB[2][256 * 64];   // 32 KB x2 (rows 0..127 w1, 128..255 w2)
    __shared__ int sTile;

    int tid = threadIdx.x;
    int lane = tid & 63;
    int wv = tid >> 6;               // 0..7
    int wm = wv >> 2, wn = wv & 3;   // 2m x 4n
    int l3 = lane >> 3;
    int l15 = lane & 15, l4 = lane >> 4;
    int srcc = (((lane & 7) ^ l3) << 3);   // pre-swizzled source column (elements)

    int ntile = meta[17] * NTB1;

    for (;;) {
        if (tid == 0) sTile = atomicAdd(&meta[18], 1);
        __syncthreads();
        int t = sTile;
        if (t >= ntile) break;

        int bm = t / NTB1, bn = t - bm * NTB1;
        int e  = meta[32 + 2 * bm];
        int m0 = meta[33 + 2 * bm];
        int mEnd = meta[9 + e];
        int mEndm1 = mEnd - 1;
        int n0 = bn * 128;

        const unsigned short* w1e = w1b + (size_t)e * HPAD2 * CDIM + (size_t)n0 * CDIM;
        const unsigned short* w2e = w2b + (size_t)e * HPAD2 * CDIM + (size_t)n0 * CDIM;
        const unsigned short* bbase = (wv < 4) ? w1e : w2e;

        f32x4 acc1[8][2], acc2[8][2];
#pragma unroll
        for (int i = 0; i < 8; ++i)
#pragma unroll
            for (int j = 0; j < 2; ++j) {
                acc1[i][j] = {0.f, 0.f, 0.f, 0.f};
                acc2[i][j] = {0.f, 0.f, 0.f, 0.f};
            }

        auto STAGE_A = [&](int b, int kk) {
            int k0 = kk * 64;
#pragma unroll
            for (int i_ = 0; i_ < 4; ++i_) {
                int seg = wv * 4 + i_;
                int arow = seg * 8 + l3;
                int grow = m0 + arow; if (grow > mEndm1) grow = mEndm1;
                gl_lds16(Xg + (size_t)grow * CDIM + k0 + srcc, sA[b] + seg * 512);
            }
        };
        auto STAGE_B = [&](int b, int kk) {
            int k0 = kk * 64;
#pragma unroll
            for (int i_ = 0; i_ < 4; ++i_) {
                int seg = wv * 4 + i_;
                int bseg = (wv < 4) ? seg : seg - 16;
                gl_lds16(bbase + (size_t)(bseg * 8 + l3) * CDIM + k0 + srcc, sB[b] + seg * 512);
            }
        };

        STAGE_A(0, 0); STAGE_B(0, 0);
        STAGE_A(1, 1); STAGE_B(1, 1);          // 16 loads/wave in flight
        asm volatile("s_waitcnt vmcnt(8)" ::: "memory");   // tile0's 8 done
        __builtin_amdgcn_s_barrier();

        for (int t_ = 0; t_ < NT1; ++t_) {
            int cur = t_ & 1;
            const unsigned short* A = sA[cur];
            const unsigned short* B = sB[cur];
            bf16x8 af[2][4], b1f[2][2], b2f[2][2];

            // ---- P0: read af_lo + b1f ; MFMA af_lo x b1 ----
#pragma unroll
            for (int ks = 0; ks < 2; ++ks) {
                int kch = ks * 4 + l4;
#pragma unroll
                for (int i = 0; i < 4; ++i)
                    af[ks][i] = *(const bf16x8*)(A + SWZ(wm * 128 + i * 16 + l15, kch));
#pragma unroll
                for (int j = 0; j < 2; ++j)
                    b1f[ks][j] = *(const bf16x8*)(B + SWZ(wn * 32 + j * 16 + l15, kch));
            }
            __builtin_amdgcn_s_barrier();
            asm volatile("s_waitcnt lgkmcnt(0)" ::: "memory");
            __builtin_amdgcn_s_setprio(1);
#pragma unroll
            for (int ks = 0; ks < 2; ++ks)
#pragma unroll
                for (int i = 0; i < 4; ++i)
#pragma unroll
                    for (int j = 0; j < 2; ++j)
                        acc1[i][j] = __builtin_amdgcn_mfma_f32_16x16x32_bf16(af[ks][i], b1f[ks][j], acc1[i][j], 0, 0, 0);
            __builtin_amdgcn_s_setprio(0);
            __builtin_amdgcn_s_barrier();

            // ---- P1: read b2f ; MFMA af_lo x b2 ----
#pragma unroll
            for (int ks = 0; ks < 2; ++ks) {
                int kch = ks * 4 + l4;
#pragma unroll
                for (int j = 0; j < 2; ++j)
                    b2f[ks][j] = *(const bf16x8*)(B + SWZ(128 + wn * 32 + j * 16 + l15, kch));
            }
            __builtin_amdgcn_s_barrier();
            asm volatile("s_waitcnt lgkmcnt(0)" ::: "memory");
            __builtin_amdgcn_s_setprio(1);
#pragma unroll
            for (int ks = 0; ks < 2; ++ks)
#pragma unroll
                for (int i = 0; i < 4; ++i)
#pragma unroll
                    for (int j = 0; j < 2; ++j)
                        acc2[i][j] = __builtin_amdgcn_mfma_f32_16x16x32_bf16(af[ks][i], b2f[ks][j], acc2[i][j], 0, 0, 0);
            __builtin_amdgcn_s_setprio(0);
            __builtin_amdgcn_s_barrier();

            // ---- P2: read af_hi ; stage B(t+2) ; MFMA af_hi x b1 ----
#pragma unroll
            for (int ks = 0; ks < 2; ++ks) {
                int kch = ks * 4 + l4;
#pragma unroll
                for (int i = 0; i < 4; ++i)
                    af[ks][i] = *(const bf16x8*)(A + SWZ(wm * 128 + 64 + i * 16 + l15, kch));
            }
            if (t_ + 2 < NT1) STAGE_B(cur, t_ + 2);
            __builtin_amdgcn_s_barrier();
            asm volatile("s_waitcnt lgkmcnt(0)" ::: "memory");
            __builtin_amdgcn_s_setprio(1);
#pragma unroll
            for (int ks = 0; ks < 2; ++ks)
#pragma unroll
                for (int i = 0; i < 4; ++i)
#pragma unroll
                    for (int j = 0; j < 2; ++j)
                        acc1[4 + i][j] = __builtin_amdgcn_mfma_f32_16x16x32_bf16(af[ks][i], b1f[ks][j], acc1[4 + i][j], 0, 0, 0);
            __builtin_amdgcn_s_setprio(0);
            __builtin_amdgcn_s_barrier();

            // ---- P3: stage A(t+2) ; counted vmcnt ; MFMA af_hi x b2 ----
            if (t_ + 2 < NT1) {
                STAGE_A(cur, t_ + 2);
                asm volatile("s_waitcnt vmcnt(8)" ::: "memory");   // tile t+1's 8 done
            } else {
                asm volatile("s_waitcnt vmcnt(0)" ::: "memory");
            }
            __builtin_amdgcn_s_barrier();
            __builtin_amdgcn_s_setprio(1);
#pragma unroll
            for (int ks = 0; ks < 2; ++ks)
#pragma unroll
                for (int i = 0; i < 4; ++i)
#pragma unroll
                    for (int j = 0; j < 2; ++j)
                        acc2[4 + i][j] = __builtin_amdgcn_mfma_f32_16x16x32_bf16(af[ks][i], b2f[ks][j], acc2[4 + i][j], 0, 0, 0);
            __builtin_amdgcn_s_setprio(0);
            __builtin_amdgcn_s_barrier();
        }

        // epilogue: act = silu(h1)*h2*pair_w (bf16); register-only
#pragma unroll
        for (int i = 0; i < 8; ++i) {
            int rbase = m0 + wm * 128 + ((i & 3) * 16) + ((i >> 2) * 64) + (l4 << 2);
#pragma unroll
            for (int r = 0; r < 4; ++r) {
                int grow = rbase + r;
                if (grow >= mEnd) continue;
                float pw = pair_w[grow];
                size_t rowoff = (size_t)grow * HPAD2;
#pragma unroll
                for (int j = 0; j < 2; ++j) {
                    int gcol = n0 + wn * 32 + j * 16 + l15;
                    int ai = (i & 3) + ((i >> 2) << 2);
                    float h1 = acc1[ai][j][r], h2 = acc2[ai][j][r];
                    float a = (h1 / (1.f + __expf(-h1))) * h2 * pw;
                    act[rowoff + gcol] = f2bf(a);
                }
            }
        }
    }
}

// GEMM2 (R5 form): tile 128m x 128n, 512 threads, 8 waves (2m x 4n), wave 64x32, dbuf.
// out[token] += act * w3b^T. Exactly 2 fp32 atomicAdds per element -> bitwise stable.
__global__ __launch_bounds__(512, 2) void moe_gemm2(
    const unsigned short* __restrict__ act,
    const unsigned short* __restrict__ w3b,
    int* __restrict__ meta, const int* __restrict__ pair_token,
    float* __restrict__ out)
{
    __shared__ unsigned short sA[2][128 * 64];   // 16 KB x2
    __shared__ unsigned short sB[2][128 * 64];   // 16 KB x2
    __shared__ int sTile;

    int tid = threadIdx.x;
    int lane = tid & 63;
    int wv = tid >> 6;
    int wm = wv >> 2, wn = wv & 3;   // 2m x 4n, wave 64m x 32n
    int l3 = lane >> 3;
    int srcc = (((lane & 7) ^ l3) << 3);

    int ntile = meta[20] * NTB2;

    for (;;) {
        if (tid == 0) sTile = atomicAdd(&meta[19], 1);
        __syncthreads();
        int t = sTile;
        if (t >= ntile) break;

        int bm = t / NTB2, bn = t - bm * NTB2;
        int e  = meta[128 + 2 * bm];
        int m0 = meta[129 + 2 * bm];
        int mEnd = meta[9 + e];
        int mEndm1 = mEnd - 1;
        int n0 = bn * 128;

        const unsigned short* w3e = w3b + (size_t)e * CDIM * HPAD2 + (size_t)n0 * HPAD2;

        f32x4 acc[4][2];
#pragma unroll
        for (int i = 0; i < 4; ++i)
#pragma unroll
            for (int j = 0; j < 2; ++j) acc[i][j] = {0.f, 0.f, 0.f, 0.f};

        auto STAGE = [&](int b, int kk) {
            int k0 = kk * 64;
#pragma unroll
            for (int i_ = 0; i_ < 2; ++i_) {
                int seg = wv * 2 + i_;
                int row = seg * 8 + l3;
                int grow = m0 + row; if (grow > mEndm1) grow = mEndm1;
                gl_lds16(act + (size_t)grow * HPAD2 + k0 + srcc, sA[b] + seg * 512);
                gl_lds16(w3e + (size_t)row * HPAD2 + k0 + srcc, sB[b] + seg * 512);
            }
        };

        STAGE(0, 0);
        __syncthreads();
        for (int t_ = 0; t_ < NT2; ++t_) {
            int cur = t_ & 1;
            if (t_ + 1 < NT2) STAGE(cur ^ 1, t_ + 1);
#pragma unroll
            for (int ks = 0; ks < 2; ++ks) {
                int kch = ks * 4 + (lane >> 4);
                bf16x8 af[4], bf[2];
#pragma unroll
                for (int i = 0; i < 4; ++i) {
                    int r = wm * 64 + i * 16 + (lane & 15);
                    af[i] = *(const bf16x8*)(sA[cur] + SWZ(r, kch));
                }
#pragma unroll
                for (int j = 0; j < 2; ++j) {
                    int r = wn * 32 + j * 16 + (lane & 15);
                    bf[j] = *(const bf16x8*)(sB[cur] + SWZ(r, kch));
                }
#pragma unroll
                for (int i = 0; i < 4; ++i)
#pragma unroll
                    for (int j = 0; j < 2; ++j)
                        acc[i][j] = __builtin_amdgcn_mfma_f32_16x16x32_bf16(af[i], bf[j], acc[i][j], 0, 0, 0);
            }
            __syncthreads();
        }

#pragma unroll
        for (int i = 0; i < 4; ++i) {
            int rbase = m0 + wm * 64 + i * 16 + ((lane >> 4) << 2);
#pragma unroll
            for (int r = 0; r < 4; ++r) {
                int grow = rbase + r;
                if (grow >= mEnd) continue;
                int tok = pair_token[grow];
                float* orow = out + (size_t)tok * CDIM;
#pragma unroll
                for (int j = 0; j < 2; ++j) {
                    int gcol = n0 + wn * 32 + j * 16 + (lane & 15);
                    atomicAdd(orow + gcol, acc[i][j][r]);
                }
            }
        }
    }
}

extern "C" void kernel_launch(void* const* d_in, const int* in_sizes, int n_in,
                              void* d_out, int out_size, void* d_ws, size_t ws_size,
                              hipStream_t stream)
{
    const float* x  = (const float*)d_in[0];
    const float* gw = (const float*)d_in[1];
    const float* w1 = (const float*)d_in[2];
    const float* w2 = (const float*)d_in[3];
    const float* w3 = (const float*)d_in[4];
    float* out = (float*)d_out;

    char* ws = (char*)d_ws;
    size_t off = 0;
    auto alloc = [&](size_t bytes) -> void* {
        off = (off + 255) & ~(size_t)255;
        void* p = ws + off;
        off += bytes;
        return p;
    };
    int*   meta       = (int*)alloc(512 * sizeof(int));
    int*   tok_idx    = (int*)alloc((size_t)NPAIR * sizeof(int));
    float* tok_w      = (float*)alloc((size_t)NPAIR * sizeof(float));
    int*   pair_token = (int*)alloc((size_t)NPAIR * sizeof(int));
    float* pair_w     = (float*)alloc((size_t)NPAIR * sizeof(float));
    unsigned short* Xg  = (unsigned short*)alloc((size_t)NPAIR * CDIM * 2);
    unsigned short* act = (unsigned short*)alloc((size_t)NPAIR * HPAD2 * 2);
    unsigned short* w1b = (unsigned short*)alloc((size_t)NEXP * HPAD2 * CDIM * 2);
    unsigned short* w2b = (unsigned short*)alloc((size_t)NEXP * HPAD2 * CDIM * 2);
    unsigned short* w3b = (unsigned short*)alloc((size_t)NEXP * CDIM * HPAD2 * 2);
    (void)ws_size; (void)in_sizes; (void)n_in; (void)out_size;

    moe_zero<<<1024, 256, 0, stream>>>(meta, out);
    moe_router<<<TOKENS / 4, 256, 0, stream>>>(x, gw, meta, tok_idx, tok_w);
    moe_scan<<<1, 64, 0, stream>>>(meta);
    moe_scatter<<<TOKENS / 256, 256, 0, stream>>>(tok_idx, tok_w, meta, pair_token, pair_w);
    moe_gather<<<NPAIR / 8, 256, 0, stream>>>(x, pair_token, Xg);
    conv_all<<<dim3(HPAD2 / 8, NEXP, 3), 256, 0, stream>>>(w1, w2, w3, w1b, w2b, w3b);
    moe_gemm1<<<256, 512, 0, stream>>>(Xg, w1b, w2b, pair_w, meta, act);
    moe_gemm2<<<512, 512, 0, stream>>>(act, w3b, meta, pair_token, out);
}